// Round 2
// baseline (274.642 us; speedup 1.0000x reference)
//
#include <hip/hip_runtime.h>
#include <hip/hip_bf16.h>
#include <stdint.h>

#define IN_F   4096
#define OUT_F  4096
#define M_ROWS 2048
#define NG     32
#define GRP    128

typedef __bf16 bf16x8 __attribute__((ext_vector_type(8)));
typedef float  f32x4  __attribute__((ext_vector_type(4)));

typedef const void __attribute__((address_space(1))) cv_g;
typedef void       __attribute__((address_space(3))) v_l;

__device__ __forceinline__ void async16(const void* g, void* l) {
  // global -> LDS DMA, 16B/lane; LDS dest is wave-uniform base + lane*16,
  // global address is per-lane arbitrary (m104/m108) -- we exploit that for swizzle.
  __builtin_amdgcn_global_load_lds((cv_g*)g, (v_l*)l, 16, 0, 0);
}

// perm dtype flag (fallback path only): 1 if int64, 0 if int32.
__device__ int g_perm_is64;

__global__ void decode_flag(const void* __restrict__ perm_raw) {
  if (threadIdx.x == 0 && blockIdx.x == 0) {
    const int* w = (const int*)perm_raw;
    int ok = 1;
    for (int j = 0; j < 32; ++j) {
      int lo = w[2 * j], hi = w[2 * j + 1];
      if (hi != 0 || lo < 0 || lo >= IN_F) { ok = 0; break; }
    }
    g_perm_is64 = ok;
  }
}

// xp[m, j] = bf16( x[m, perm[j]] ).  One block per row: coalesced row load into
// LDS, gather from LDS (fast), packed 16B stores.  perm dtype detected via ballot.
__global__ __launch_bounds__(256) void gather_x(const float* __restrict__ x,
                                                const void* __restrict__ perm_raw,
                                                __hip_bfloat16* __restrict__ xp) {
  __shared__ float sx[IN_F];
  __shared__ int sflag;
  const int m = blockIdx.x;
  const int t = threadIdx.x;
  const float* xr = x + (size_t)m * IN_F;
#pragma unroll
  for (int u = 0; u < 4; ++u) {
    int idx = (u * 256 + t) * 4;
    *(float4*)&sx[idx] = *(const float4*)&xr[idx];
  }
  if (t < 64) {
    const int* w = (const int*)perm_raw;
    int j = t & 31;  // lanes 32..63 duplicate lanes 0..31 -> same ballot bits
    int lo = w[2 * j], hi = w[2 * j + 1];
    // int64 little-endian values in [0,4096): hi word always 0. int32 perm:
    // w[2j+1] is a perm value, ==0 for at most one j -> ballot never full.
    int cond = (hi == 0 && lo >= 0 && lo < IN_F);
    unsigned long long b = __ballot(cond);
    if (t == 0) sflag = (b == ~0ull) ? 1 : 0;
  }
  __syncthreads();
  const int f = sflag;
  const long long* p64 = (const long long*)perm_raw;
  const int*       p32 = (const int*)perm_raw;
  const int jb = t * 16;
  __hip_bfloat16 tmp[16] __attribute__((aligned(16)));
#pragma unroll
  for (int u = 0; u < 16; ++u) {
    int pj = f ? (int)p64[jb + u] : p32[jb + u];
    tmp[u] = __float2bfloat16(sx[pj]);
  }
  *(uint4*)(xp + (size_t)m * IN_F + jb)     = *(const uint4*)&tmp[0];
  *(uint4*)(xp + (size_t)m * IN_F + jb + 8) = *(const uint4*)&tmp[8];
}

// wf[o, k] = bf16( w_q[o,k] * s_w[k/128, o] ) -- group scale folded into weight.
__global__ __launch_bounds__(256) void conv_w(const int* __restrict__ w_q,
                                              const float* __restrict__ s_w,
                                              __hip_bfloat16* __restrict__ wf) {
  int t  = blockIdx.x * blockDim.x + threadIdx.x;  // 0 .. 4096*512-1
  int o  = t >> 9;
  int kb = (t & 511) << 3;                          // 8 consecutive k, one group (8|128)
  float s = s_w[(size_t)(kb >> 7) * OUT_F + o];
  const int* wr = w_q + (size_t)o * IN_F + kb;
  int4 w0 = *(const int4*)wr;
  int4 w1 = *(const int4*)(wr + 4);
  __hip_bfloat16 tmp[8] __attribute__((aligned(16)));
  tmp[0] = __float2bfloat16((float)w0.x * s);
  tmp[1] = __float2bfloat16((float)w0.y * s);
  tmp[2] = __float2bfloat16((float)w0.z * s);
  tmp[3] = __float2bfloat16((float)w0.w * s);
  tmp[4] = __float2bfloat16((float)w1.x * s);
  tmp[5] = __float2bfloat16((float)w1.y * s);
  tmp[6] = __float2bfloat16((float)w1.z * s);
  tmp[7] = __float2bfloat16((float)w1.w * s);
  *(uint4*)(wf + (size_t)o * IN_F + kb) = *(const uint4*)tmp;
}

// C[m,o] = sum_k A[m,k]*B[o,k] + bias[o]; A: M x K bf16, B: N x K bf16.
// 128x128 tile, BK=64, double-buffered LDS (64 KB), 4 waves (2x2), each wave
// 64x64 via 4x4 MFMA 16x16x32 over 2 k-steps.
// LDS tile layout is FRAGMENT-ORDERED: [rowblock 0..7][kchunk 0..7][row%16] x 16B,
// so fragment reads by a quarter-wave are 256B contiguous -> conflict-free.
// Staging achieves this by lane-permuting the GLOBAL address (dest is lane-ordered).
__global__ __launch_bounds__(256) void gemm_bt(
    const __hip_bfloat16* __restrict__ A,
    const __hip_bfloat16* __restrict__ B,
    const float* __restrict__ bias,
    float* __restrict__ C) {
  __shared__ __hip_bfloat16 smem[32768];  // [parity 0/1][A 8192 | B 8192] elems = 64 KB

  const int tid  = threadIdx.x;
  const int wave = tid >> 6;
  const int lane = tid & 63;
  const int bm = blockIdx.y << 7;
  const int bn = blockIdx.x << 7;
  const int lrow = lane & 15;
  const int quad = lane >> 4;

  f32x4 acc[4][4] = {};

  // Staging geometry: linear chunk L = rowblock*128 + kchunk*16 + (row&15),
  // LDS elem offset = L*8. Wave w, round h covers L = h*256 + w*64 + lane.
  const __hip_bfloat16* gA[4];
  const __hip_bfloat16* gB[4];
  int loff[4];
#pragma unroll
  for (int h = 0; h < 4; ++h) {
    int L   = h * 256 + wave * 64 + lane;
    int row = ((L >> 7) << 4) + (L & 15);
    int kc  = (L >> 4) & 7;
    gA[h] = A + (size_t)(bm + row) * IN_F + kc * 8;
    gB[h] = B + (size_t)(bn + row) * IN_F + kc * 8;
    loff[h] = L * 8;
  }

  // Fragment read bases (elements): rowblock*1024 + s*512 + quad*128 + lrow*8
  const int aoff = (wave >> 1) * 4096 + quad * 128 + lrow * 8;
  const int boff = (wave & 1) * 4096 + quad * 128 + lrow * 8;

  // Prologue: stage k0=0 into parity 0.
#pragma unroll
  for (int h = 0; h < 4; ++h) {
    async16(gA[h], &smem[loff[h]]);
    async16(gB[h], &smem[8192 + loff[h]]);
  }

  __hip_bfloat16* buf0 = &smem[0];
  __hip_bfloat16* buf1 = &smem[16384];

  auto do_iter = [&](const __hip_bfloat16* cur, __hip_bfloat16* nxt, int kn) {
    __syncthreads();  // vmcnt drain: prev stage had a full compute phase to land
    if (kn < IN_F) {
#pragma unroll
      for (int h = 0; h < 4; ++h) {
        async16(gA[h] + kn, nxt + loff[h]);
        async16(gB[h] + kn, nxt + 8192 + loff[h]);
      }
    }
#pragma unroll
    for (int s = 0; s < 2; ++s) {
      bf16x8 af[4], bfr[4];
#pragma unroll
      for (int i = 0; i < 4; ++i)
        af[i] = *(const bf16x8*)&cur[aoff + i * 1024 + s * 512];
#pragma unroll
      for (int j = 0; j < 4; ++j)
        bfr[j] = *(const bf16x8*)&cur[8192 + boff + j * 1024 + s * 512];
#pragma unroll
      for (int i = 0; i < 4; ++i)
#pragma unroll
        for (int j = 0; j < 4; ++j)
          acc[i][j] = __builtin_amdgcn_mfma_f32_16x16x32_bf16(af[i], bfr[j], acc[i][j], 0, 0, 0);
    }
  };

  for (int k0 = 0; k0 < IN_F; k0 += 128) {
    do_iter(buf0, buf1, k0 + 64);
    do_iter(buf1, buf0, k0 + 128);
  }

  // Epilogue: C/D layout col=lane&15, row=quad*4+reg  [measured m89/m91]
  const int wm = (wave >> 1) << 6;
  const int wn = (wave & 1) << 6;
#pragma unroll
  for (int i = 0; i < 4; ++i) {
    int row = bm + wm + i * 16 + quad * 4;
#pragma unroll
    for (int j = 0; j < 4; ++j) {
      int col = bn + wn + j * 16 + lrow;
      float bv = bias[col];
#pragma unroll
      for (int r = 0; r < 4; ++r)
        C[(size_t)(row + r) * OUT_F + col] = acc[i][j][r] + bv;
    }
  }
}

// Correct-but-slow fp32 fallback if workspace is too small for bf16 staging.
__global__ void naive_fallback(const float* __restrict__ x, const int* __restrict__ w_q,
                               const float* __restrict__ s_w, const void* __restrict__ perm_raw,
                               const float* __restrict__ bias, float* __restrict__ out) {
  int t = blockIdx.x * blockDim.x + threadIdx.x;
  int m = t >> 12;
  int o = t & 4095;
  const int f = g_perm_is64;
  const long long* p64 = (const long long*)perm_raw;
  const int*       p32 = (const int*)perm_raw;
  const float* xr = x + (size_t)m * IN_F;
  const int*   wr = w_q + (size_t)o * IN_F;
  float acc = 0.f;
  for (int g = 0; g < NG; ++g) {
    float part = 0.f;
    for (int k = 0; k < GRP; ++k) {
      int j = g * GRP + k;
      int pj = f ? (int)p64[j] : p32[j];
      part += xr[pj] * (float)wr[j];
    }
    acc += part * s_w[(size_t)g * OUT_F + o];
  }
  out[t] = acc + bias[o];
}

extern "C" void kernel_launch(void* const* d_in, const int* in_sizes, int n_in,
                              void* d_out, int out_size, void* d_ws, size_t ws_size,
                              hipStream_t stream) {
  const float* x    = (const float*)d_in[0];
  const int*   w_q  = (const int*)d_in[1];
  const float* s_w  = (const float*)d_in[2];
  const void*  perm = d_in[3];   // int64 or int32 -- detected on device
  const float* bias = (const float*)d_in[4];
  float* out = (float*)d_out;

  const size_t xp_bytes = (size_t)M_ROWS * IN_F * sizeof(__hip_bfloat16);  // 16 MiB
  const size_t wf_bytes = (size_t)OUT_F * IN_F * sizeof(__hip_bfloat16);   // 32 MiB

  if (ws_size < xp_bytes + wf_bytes) {
    decode_flag<<<1, 64, 0, stream>>>(perm);
    naive_fallback<<<(M_ROWS * OUT_F) / 256, 256, 0, stream>>>(x, w_q, s_w, perm, bias, out);
    return;
  }

  __hip_bfloat16* xp = (__hip_bfloat16*)d_ws;
  __hip_bfloat16* wf = (__hip_bfloat16*)((char*)d_ws + xp_bytes);

  gather_x<<<M_ROWS, 256, 0, stream>>>(x, perm, xp);
  conv_w<<<(OUT_F * IN_F / 8) / 256, 256, 0, stream>>>(w_q, s_w, wf);

  dim3 grid(OUT_F / 128, M_ROWS / 128);  // 32 x 16 = 512 blocks
  gemm_bt<<<grid, 256, 0, stream>>>(xp, wf, bias, out);
}

// Round 3
// 230.299 us; speedup vs baseline: 1.1925x; 1.1925x over previous
//
#include <hip/hip_runtime.h>
#include <hip/hip_bf16.h>
#include <stdint.h>

#define IN_F   4096
#define OUT_F  4096
#define M_ROWS 2048
#define NG     32
#define GRP    128

typedef __bf16 bf16x8 __attribute__((ext_vector_type(8)));
typedef float  f32x4  __attribute__((ext_vector_type(4)));

typedef const void __attribute__((address_space(1))) cv_g;
typedef void       __attribute__((address_space(3))) v_l;

__device__ __forceinline__ void async16(const void* g, void* l) {
  // global -> LDS DMA, 16B/lane; LDS dest = wave-uniform base + lane*16.
  __builtin_amdgcn_global_load_lds((cv_g*)g, (v_l*)l, 16, 0, 0);
}

// perm dtype flag (fallback path only): 1 if int64, 0 if int32.
__device__ int g_perm_is64;

__global__ void decode_flag(const void* __restrict__ perm_raw) {
  if (threadIdx.x == 0 && blockIdx.x == 0) {
    const int* w = (const int*)perm_raw;
    int ok = 1;
    for (int j = 0; j < 32; ++j) {
      int lo = w[2 * j], hi = w[2 * j + 1];
      if (hi != 0 || lo < 0 || lo >= IN_F) { ok = 0; break; }
    }
    g_perm_is64 = ok;
  }
}

// Fused preprocessing:
//   blocks [0, 2048):     xp[m, j] = bf16( x[m, perm[j]] )  (LDS-staged row gather)
//   blocks [2048, 10240): wf[o, k] = bf16( w_q[o,k] * s_w[k/128, o] )
// Fusing lets the two memory-bound phases co-schedule across CUs instead of
// serializing as back-to-back dispatches.
__global__ __launch_bounds__(256) void prep(const float* __restrict__ x,
                                            const int* __restrict__ w_q,
                                            const float* __restrict__ s_w,
                                            const void* __restrict__ perm_raw,
                                            __hip_bfloat16* __restrict__ xp,
                                            __hip_bfloat16* __restrict__ wf) {
  __shared__ float sx[IN_F];
  __shared__ int sflag;
  const int b = blockIdx.x;
  const int t = threadIdx.x;

  if (b < M_ROWS) {
    // ---- gather_x: one block per row ----
    const int m = b;
    const float* xr = x + (size_t)m * IN_F;
#pragma unroll
    for (int u = 0; u < 4; ++u) {
      int idx = (u * 256 + t) * 4;
      *(float4*)&sx[idx] = *(const float4*)&xr[idx];
    }
    if (t < 64) {
      const int* w = (const int*)perm_raw;
      int j = t & 31;  // lanes 32..63 duplicate 0..31 -> same ballot bits
      int lo = w[2 * j], hi = w[2 * j + 1];
      // int64 LE values in [0,4096): hi word always 0. int32 perm: w[2j+1] is a
      // perm value, ==0 for at most one j -> ballot never all-ones.
      int cond = (hi == 0 && lo >= 0 && lo < IN_F);
      unsigned long long bal = __ballot(cond);
      if (t == 0) sflag = (bal == ~0ull) ? 1 : 0;
    }
    __syncthreads();
    const int f = sflag;
    const long long* p64 = (const long long*)perm_raw;
    const int*       p32 = (const int*)perm_raw;
    const int jb = t * 16;
    __hip_bfloat16 tmp[16] __attribute__((aligned(16)));
#pragma unroll
    for (int u = 0; u < 16; ++u) {
      int pj = f ? (int)p64[jb + u] : p32[jb + u];
      tmp[u] = __float2bfloat16(sx[pj]);
    }
    *(uint4*)(xp + (size_t)m * IN_F + jb)     = *(const uint4*)&tmp[0];
    *(uint4*)(xp + (size_t)m * IN_F + jb + 8) = *(const uint4*)&tmp[8];
  } else {
    // ---- conv_w: 8 consecutive k per thread (one group: 8 | 128) ----
    int tt = (b - M_ROWS) * 256 + t;            // 0 .. 4096*512-1
    int o  = tt >> 9;
    int kb = (tt & 511) << 3;
    float s = s_w[(size_t)(kb >> 7) * OUT_F + o];
    const int* wr = w_q + (size_t)o * IN_F + kb;
    int4 w0 = *(const int4*)wr;
    int4 w1 = *(const int4*)(wr + 4);
    __hip_bfloat16 tmp[8] __attribute__((aligned(16)));
    tmp[0] = __float2bfloat16((float)w0.x * s);
    tmp[1] = __float2bfloat16((float)w0.y * s);
    tmp[2] = __float2bfloat16((float)w0.z * s);
    tmp[3] = __float2bfloat16((float)w0.w * s);
    tmp[4] = __float2bfloat16((float)w1.x * s);
    tmp[5] = __float2bfloat16((float)w1.y * s);
    tmp[6] = __float2bfloat16((float)w1.z * s);
    tmp[7] = __float2bfloat16((float)w1.w * s);
    *(uint4*)(wf + (size_t)o * IN_F + kb) = *(const uint4*)tmp;
  }
}

// C[m,o] = sum_k A[m,k]*B[o,k] + bias[o]; A: M x K bf16, B: N x K bf16.
// R1 structure: 128x128 tile, BK=32, single 16 KB x2 LDS buffer, 4 waves (2x2),
// each wave 64x64 via 4x4 MFMA 16x16x32.
// NEW vs R1: XOR bank swizzle. Chunk (row, kc) lives at LDS position
// row*4 + (kc ^ ((row>>1)&3)). Staging quads still cover one contiguous 64B
// global segment (chunks permuted within it) -> R1 coalescing preserved; each
// 16-lane read phase now hits 8 distinct bank-groups (2-way, free) not 2 (8-way).
__global__ __launch_bounds__(256) void gemm_bt(
    const __hip_bfloat16* __restrict__ A,
    const __hip_bfloat16* __restrict__ B,
    const float* __restrict__ bias,
    float* __restrict__ C) {
  __shared__ __hip_bfloat16 sA[128 * 32];
  __shared__ __hip_bfloat16 sB[128 * 32];

  const int tid  = threadIdx.x;
  const int wave = tid >> 6;
  const int lane = tid & 63;
  const int bm = blockIdx.y << 7;
  const int bn = blockIdx.x << 7;
  const int wm = (wave >> 1) << 6;
  const int wn = (wave & 1) << 6;
  const int lrow = lane & 15;
  const int quad = lane >> 4;
  const int qx   = (quad ^ ((lrow >> 1) & 3)) << 3;  // swizzled k-chunk (elems)

  f32x4 acc[4][4] = {};

  // Staging: chunk c = wave*64 + lane (+256 for second half) -> LDS pos c,
  // global (row = c>>2, kc = (c&3) ^ ((row>>1)&3)).
  const int srow = (wave << 4) + (lane >> 2);  // 0..63; f(row) invariant under +64
  const int sq   = (lane & 3) ^ ((srow >> 1) & 3);
  const __hip_bfloat16* gA0 = A + (size_t)(bm + srow) * IN_F + sq * 8;
  const __hip_bfloat16* gA1 = gA0 + (size_t)64 * IN_F;
  const __hip_bfloat16* gB0 = B + (size_t)(bn + srow) * IN_F + sq * 8;
  const __hip_bfloat16* gB1 = gB0 + (size_t)64 * IN_F;
  __hip_bfloat16* lA0 = &sA[wave * 512];   // wave-uniform LDS bases
  __hip_bfloat16* lA1 = lA0 + 2048;
  __hip_bfloat16* lB0 = &sB[wave * 512];
  __hip_bfloat16* lB1 = lB0 + 2048;

  for (int k0 = 0; k0 < IN_F; k0 += 32) {
    async16(gA0 + k0, lA0);
    async16(gA1 + k0, lA1);
    async16(gB0 + k0, lB0);
    async16(gB1 + k0, lB1);
    __syncthreads();  // vmcnt drain -> staged data visible

    bf16x8 af[4], bfr[4];
#pragma unroll
    for (int i = 0; i < 4; ++i)
      af[i] = *(const bf16x8*)&sA[(wm + i * 16 + lrow) * 32 + qx];
#pragma unroll
    for (int j = 0; j < 4; ++j)
      bfr[j] = *(const bf16x8*)&sB[(wn + j * 16 + lrow) * 32 + qx];

#pragma unroll
    for (int i = 0; i < 4; ++i)
#pragma unroll
      for (int j = 0; j < 4; ++j)
        acc[i][j] = __builtin_amdgcn_mfma_f32_16x16x32_bf16(af[i], bfr[j], acc[i][j], 0, 0, 0);

    __syncthreads();  // protect LDS from next iteration's staging
  }

  // Epilogue: C/D layout col=lane&15, row=quad*4+reg  [measured m89/m91]
#pragma unroll
  for (int i = 0; i < 4; ++i) {
    int row = bm + wm + i * 16 + quad * 4;
#pragma unroll
    for (int j = 0; j < 4; ++j) {
      int col = bn + wn + j * 16 + lrow;
      float bv = bias[col];
#pragma unroll
      for (int r = 0; r < 4; ++r)
        C[(size_t)(row + r) * OUT_F + col] = acc[i][j][r] + bv;
    }
  }
}

// Correct-but-slow fp32 fallback if workspace is too small for bf16 staging.
__global__ void naive_fallback(const float* __restrict__ x, const int* __restrict__ w_q,
                               const float* __restrict__ s_w, const void* __restrict__ perm_raw,
                               const float* __restrict__ bias, float* __restrict__ out) {
  int t = blockIdx.x * blockDim.x + threadIdx.x;
  int m = t >> 12;
  int o = t & 4095;
  const int f = g_perm_is64;
  const long long* p64 = (const long long*)perm_raw;
  const int*       p32 = (const int*)perm_raw;
  const float* xr = x + (size_t)m * IN_F;
  const int*   wr = w_q + (size_t)o * IN_F;
  float acc = 0.f;
  for (int g = 0; g < NG; ++g) {
    float part = 0.f;
    for (int k = 0; k < GRP; ++k) {
      int j = g * GRP + k;
      int pj = f ? (int)p64[j] : p32[j];
      part += xr[pj] * (float)wr[j];
    }
    acc += part * s_w[(size_t)g * OUT_F + o];
  }
  out[t] = acc + bias[o];
}

extern "C" void kernel_launch(void* const* d_in, const int* in_sizes, int n_in,
                              void* d_out, int out_size, void* d_ws, size_t ws_size,
                              hipStream_t stream) {
  const float* x    = (const float*)d_in[0];
  const int*   w_q  = (const int*)d_in[1];
  const float* s_w  = (const float*)d_in[2];
  const void*  perm = d_in[3];   // int64 or int32 -- detected on device
  const float* bias = (const float*)d_in[4];
  float* out = (float*)d_out;

  const size_t xp_bytes = (size_t)M_ROWS * IN_F * sizeof(__hip_bfloat16);  // 16 MiB
  const size_t wf_bytes = (size_t)OUT_F * IN_F * sizeof(__hip_bfloat16);   // 32 MiB

  if (ws_size < xp_bytes + wf_bytes) {
    decode_flag<<<1, 64, 0, stream>>>(perm);
    naive_fallback<<<(M_ROWS * OUT_F) / 256, 256, 0, stream>>>(x, w_q, s_w, perm, bias, out);
    return;
  }

  __hip_bfloat16* xp = (__hip_bfloat16*)d_ws;
  __hip_bfloat16* wf = (__hip_bfloat16*)((char*)d_ws + xp_bytes);

  // gather blocks (2048) + conv blocks (4096*512/256 = 8192)
  prep<<<M_ROWS + (OUT_F * IN_F / 8) / 256, 256, 0, stream>>>(x, w_q, s_w, perm, xp, wf);

  dim3 grid(OUT_F / 128, M_ROWS / 128);  // 32 x 16 = 512 blocks
  gemm_bt<<<grid, 256, 0, stream>>>(xp, wf, bias, out);
}

// Round 4
// 219.689 us; speedup vs baseline: 1.2501x; 1.0483x over previous
//
#include <hip/hip_runtime.h>
#include <hip/hip_bf16.h>
#include <stdint.h>

#define IN_F   4096
#define OUT_F  4096
#define M_ROWS 2048
#define NG     32
#define GRP    128

typedef __bf16 bf16x8 __attribute__((ext_vector_type(8)));
typedef float  f32x4  __attribute__((ext_vector_type(4)));

typedef const void __attribute__((address_space(1))) cv_g;
typedef void       __attribute__((address_space(3))) v_l;

__device__ __forceinline__ void async16(const void* g, void* l) {
  // global -> LDS DMA, 16B/lane; LDS dest = wave-uniform base + lane*16.
  __builtin_amdgcn_global_load_lds((cv_g*)g, (v_l*)l, 16, 0, 0);
}

// perm dtype flag (fallback path only): 1 if int64, 0 if int32.
__device__ int g_perm_is64;

__global__ void decode_flag(const void* __restrict__ perm_raw) {
  if (threadIdx.x == 0 && blockIdx.x == 0) {
    const int* w = (const int*)perm_raw;
    int ok = 1;
    for (int j = 0; j < 32; ++j) {
      int lo = w[2 * j], hi = w[2 * j + 1];
      if (hi != 0 || lo < 0 || lo >= IN_F) { ok = 0; break; }
    }
    g_perm_is64 = ok;
  }
}

// Fused preprocessing (unchanged from R3 -- verified):
//   blocks [0, 2048):     xp[m, j] = bf16( x[m, perm[j]] )  (LDS-staged row gather)
//   blocks [2048, 10240): wf[o, k] = bf16( w_q[o,k] * s_w[k/128, o] )
__global__ __launch_bounds__(256) void prep(const float* __restrict__ x,
                                            const int* __restrict__ w_q,
                                            const float* __restrict__ s_w,
                                            const void* __restrict__ perm_raw,
                                            __hip_bfloat16* __restrict__ xp,
                                            __hip_bfloat16* __restrict__ wf) {
  __shared__ float sx[IN_F];
  __shared__ int sflag;
  const int b = blockIdx.x;
  const int t = threadIdx.x;

  if (b < M_ROWS) {
    const int m = b;
    const float* xr = x + (size_t)m * IN_F;
#pragma unroll
    for (int u = 0; u < 4; ++u) {
      int idx = (u * 256 + t) * 4;
      *(float4*)&sx[idx] = *(const float4*)&xr[idx];
    }
    if (t < 64) {
      const int* w = (const int*)perm_raw;
      int j = t & 31;  // lanes 32..63 duplicate 0..31 -> same ballot bits
      int lo = w[2 * j], hi = w[2 * j + 1];
      // int64 LE values in [0,4096): hi word always 0. int32 perm: w[2j+1] is a
      // perm value, ==0 for at most one j -> ballot never all-ones.
      int cond = (hi == 0 && lo >= 0 && lo < IN_F);
      unsigned long long bal = __ballot(cond);
      if (t == 0) sflag = (bal == ~0ull) ? 1 : 0;
    }
    __syncthreads();
    const int f = sflag;
    const long long* p64 = (const long long*)perm_raw;
    const int*       p32 = (const int*)perm_raw;
    const int jb = t * 16;
    __hip_bfloat16 tmp[16] __attribute__((aligned(16)));
#pragma unroll
    for (int u = 0; u < 16; ++u) {
      int pj = f ? (int)p64[jb + u] : p32[jb + u];
      tmp[u] = __float2bfloat16(sx[pj]);
    }
    *(uint4*)(xp + (size_t)m * IN_F + jb)     = *(const uint4*)&tmp[0];
    *(uint4*)(xp + (size_t)m * IN_F + jb + 8) = *(const uint4*)&tmp[8];
  } else {
    int tt = (b - M_ROWS) * 256 + t;
    int o  = tt >> 9;
    int kb = (tt & 511) << 3;
    float s = s_w[(size_t)(kb >> 7) * OUT_F + o];
    const int* wr = w_q + (size_t)o * IN_F + kb;
    int4 w0 = *(const int4*)wr;
    int4 w1 = *(const int4*)(wr + 4);
    __hip_bfloat16 tmp[8] __attribute__((aligned(16)));
    tmp[0] = __float2bfloat16((float)w0.x * s);
    tmp[1] = __float2bfloat16((float)w0.y * s);
    tmp[2] = __float2bfloat16((float)w0.z * s);
    tmp[3] = __float2bfloat16((float)w0.w * s);
    tmp[4] = __float2bfloat16((float)w1.x * s);
    tmp[5] = __float2bfloat16((float)w1.y * s);
    tmp[6] = __float2bfloat16((float)w1.z * s);
    tmp[7] = __float2bfloat16((float)w1.w * s);
    *(uint4*)(wf + (size_t)o * IN_F + kb) = *(const uint4*)tmp;
  }
}

// C[m,o] = sum_k A[m,k]*B[o,k] + bias[o]; A: M x K bf16, B: N x K bf16.
// R4: 128x128 tile, BK=64 single-buffered (32 KB LDS), 4 waves (2x2), each wave
// 64x64 via 4x4 MFMA 16x16x32 over 2 k-slices. Halves barrier count vs BK=32;
// LDS growth is free at our fixed 2 blocks/CU (grid = 512).
// LDS layout: chunk(row, kc) at position row*8 + (kc ^ (row&7)); 16B chunks.
// Fragment reads (fixed s,quad): kc' = (s*4+quad)^(lrow&7) spans all 8 bank
// granules, 2 lanes each -> 2-way, free. Staging: 8-lane groups cover one
// contiguous 128B global segment (permuted within) -> coalescing preserved.
__global__ __launch_bounds__(256) void gemm_bt(
    const __hip_bfloat16* __restrict__ A,
    const __hip_bfloat16* __restrict__ B,
    const float* __restrict__ bias,
    float* __restrict__ C) {
  __shared__ __hip_bfloat16 sA[128 * 64];
  __shared__ __hip_bfloat16 sB[128 * 64];

  const int tid  = threadIdx.x;
  const int wave = tid >> 6;
  const int lane = tid & 63;
  const int bm = blockIdx.y << 7;
  const int bn = blockIdx.x << 7;
  const int wm = (wave >> 1) << 6;
  const int wn = (wave & 1) << 6;
  const int lrow = lane & 15;
  const int quad = lane >> 4;

  f32x4 acc[4][4] = {};

  // Staging: rounds h=0..3; linear chunk L = h*256 + wave*64 + lane in [0,1024);
  // row = L>>3, kc' = L&7, global kc = kc' ^ (row&7). LDS offset = L*8 elems
  // (= wave-uniform base + lane*16B, as the DMA requires).
  const __hip_bfloat16* gA[4];
  const __hip_bfloat16* gB[4];
  __hip_bfloat16* lA[4];
  __hip_bfloat16* lB[4];
#pragma unroll
  for (int h = 0; h < 4; ++h) {
    int L   = h * 256 + wave * 64 + lane;
    int row = L >> 3;
    int kc  = (L & 7) ^ (row & 7);
    gA[h] = A + (size_t)(bm + row) * IN_F + kc * 8;
    gB[h] = B + (size_t)(bn + row) * IN_F + kc * 8;
    lA[h] = &sA[(h * 256 + wave * 64) * 8];
    lB[h] = &sB[(h * 256 + wave * 64) * 8];
  }

  for (int k0 = 0; k0 < IN_F; k0 += 64) {
#pragma unroll
    for (int h = 0; h < 4; ++h) {
      async16(gA[h] + k0, lA[h]);
      async16(gB[h] + k0, lB[h]);
    }
    __syncthreads();  // vmcnt drain -> staged data visible

#pragma unroll
    for (int s = 0; s < 2; ++s) {
      // k-slice s: lane quad holds k = s*32 + quad*8 .. +8  ->  kc = s*4+quad
      const int kcp = ((s << 2) + quad) ^ (lrow & 7);  // swizzled position
      bf16x8 af[4], bfr[4];
#pragma unroll
      for (int i = 0; i < 4; ++i)
        af[i] = *(const bf16x8*)&sA[(wm + i * 16 + lrow) * 64 + kcp * 8];
#pragma unroll
      for (int j = 0; j < 4; ++j)
        bfr[j] = *(const bf16x8*)&sB[(wn + j * 16 + lrow) * 64 + kcp * 8];
#pragma unroll
      for (int i = 0; i < 4; ++i)
#pragma unroll
        for (int j = 0; j < 4; ++j)
          acc[i][j] = __builtin_amdgcn_mfma_f32_16x16x32_bf16(af[i], bfr[j], acc[i][j], 0, 0, 0);
    }

    __syncthreads();  // protect LDS from next iteration's staging
  }

  // Epilogue: C/D layout col=lane&15, row=quad*4+reg  [measured m89/m91]
#pragma unroll
  for (int i = 0; i < 4; ++i) {
    int row = bm + wm + i * 16 + quad * 4;
#pragma unroll
    for (int j = 0; j < 4; ++j) {
      int col = bn + wn + j * 16 + lrow;
      float bv = bias[col];
#pragma unroll
      for (int r = 0; r < 4; ++r)
        C[(size_t)(row + r) * OUT_F + col] = acc[i][j][r] + bv;
    }
  }
}

// Correct-but-slow fp32 fallback if workspace is too small for bf16 staging.
__global__ void naive_fallback(const float* __restrict__ x, const int* __restrict__ w_q,
                               const float* __restrict__ s_w, const void* __restrict__ perm_raw,
                               const float* __restrict__ bias, float* __restrict__ out) {
  int t = blockIdx.x * blockDim.x + threadIdx.x;
  int m = t >> 12;
  int o = t & 4095;
  const int f = g_perm_is64;
  const long long* p64 = (const long long*)perm_raw;
  const int*       p32 = (const int*)perm_raw;
  const float* xr = x + (size_t)m * IN_F;
  const int*   wr = w_q + (size_t)o * IN_F;
  float acc = 0.f;
  for (int g = 0; g < NG; ++g) {
    float part = 0.f;
    for (int k = 0; k < GRP; ++k) {
      int j = g * GRP + k;
      int pj = f ? (int)p64[j] : p32[j];
      part += xr[pj] * (float)wr[j];
    }
    acc += part * s_w[(size_t)g * OUT_F + o];
  }
  out[t] = acc + bias[o];
}

extern "C" void kernel_launch(void* const* d_in, const int* in_sizes, int n_in,
                              void* d_out, int out_size, void* d_ws, size_t ws_size,
                              hipStream_t stream) {
  const float* x    = (const float*)d_in[0];
  const int*   w_q  = (const int*)d_in[1];
  const float* s_w  = (const float*)d_in[2];
  const void*  perm = d_in[3];   // int64 or int32 -- detected on device
  const float* bias = (const float*)d_in[4];
  float* out = (float*)d_out;

  const size_t xp_bytes = (size_t)M_ROWS * IN_F * sizeof(__hip_bfloat16);  // 16 MiB
  const size_t wf_bytes = (size_t)OUT_F * IN_F * sizeof(__hip_bfloat16);   // 32 MiB

  if (ws_size < xp_bytes + wf_bytes) {
    decode_flag<<<1, 64, 0, stream>>>(perm);
    naive_fallback<<<(M_ROWS * OUT_F) / 256, 256, 0, stream>>>(x, w_q, s_w, perm, bias, out);
    return;
  }

  __hip_bfloat16* xp = (__hip_bfloat16*)d_ws;
  __hip_bfloat16* wf = (__hip_bfloat16*)((char*)d_ws + xp_bytes);

  prep<<<M_ROWS + (OUT_F * IN_F / 8) / 256, 256, 0, stream>>>(x, w_q, s_w, perm, xp, wf);

  dim3 grid(OUT_F / 128, M_ROWS / 128);  // 32 x 16 = 512 blocks
  gemm_bt<<<grid, 256, 0, stream>>>(xp, wf, bias, out);
}

// Round 5
// 215.571 us; speedup vs baseline: 1.2740x; 1.0191x over previous
//
#include <hip/hip_runtime.h>
#include <hip/hip_bf16.h>
#include <stdint.h>

#define IN_F   4096
#define OUT_F  4096
#define M_ROWS 2048
#define NG     32
#define GRP    128

typedef __bf16 bf16x8 __attribute__((ext_vector_type(8)));
typedef float  f32x4  __attribute__((ext_vector_type(4)));

typedef const void __attribute__((address_space(1))) cv_g;
typedef void       __attribute__((address_space(3))) v_l;

__device__ __forceinline__ void async16(const void* g, void* l) {
  // global -> LDS DMA, 16B/lane; LDS dest = wave-uniform base + lane*16.
  __builtin_amdgcn_global_load_lds((cv_g*)g, (v_l*)l, 16, 0, 0);
}

// perm dtype flag (fallback path only): 1 if int64, 0 if int32.
__device__ int g_perm_is64;

__global__ void decode_flag(const void* __restrict__ perm_raw) {
  if (threadIdx.x == 0 && blockIdx.x == 0) {
    const int* w = (const int*)perm_raw;
    int ok = 1;
    for (int j = 0; j < 32; ++j) {
      int lo = w[2 * j], hi = w[2 * j + 1];
      if (hi != 0 || lo < 0 || lo >= IN_F) { ok = 0; break; }
    }
    g_perm_is64 = ok;
  }
}

// Fused preprocessing (unchanged from R3 -- verified):
//   blocks [0, 2048):     xp[m, j] = bf16( x[m, perm[j]] )  (LDS-staged row gather)
//   blocks [2048, 10240): wf[o, k] = bf16( w_q[o,k] * s_w[k/128, o] )
__global__ __launch_bounds__(256) void prep(const float* __restrict__ x,
                                            const int* __restrict__ w_q,
                                            const float* __restrict__ s_w,
                                            const void* __restrict__ perm_raw,
                                            __hip_bfloat16* __restrict__ xp,
                                            __hip_bfloat16* __restrict__ wf) {
  __shared__ float sx[IN_F];
  __shared__ int sflag;
  const int b = blockIdx.x;
  const int t = threadIdx.x;

  if (b < M_ROWS) {
    const int m = b;
    const float* xr = x + (size_t)m * IN_F;
#pragma unroll
    for (int u = 0; u < 4; ++u) {
      int idx = (u * 256 + t) * 4;
      *(float4*)&sx[idx] = *(const float4*)&xr[idx];
    }
    if (t < 64) {
      const int* w = (const int*)perm_raw;
      int j = t & 31;  // lanes 32..63 duplicate 0..31 -> same ballot bits
      int lo = w[2 * j], hi = w[2 * j + 1];
      // int64 LE values in [0,4096): hi word always 0. int32 perm: w[2j+1] is a
      // perm value, ==0 for at most one j -> ballot never all-ones.
      int cond = (hi == 0 && lo >= 0 && lo < IN_F);
      unsigned long long bal = __ballot(cond);
      if (t == 0) sflag = (bal == ~0ull) ? 1 : 0;
    }
    __syncthreads();
    const int f = sflag;
    const long long* p64 = (const long long*)perm_raw;
    const int*       p32 = (const int*)perm_raw;
    const int jb = t * 16;
    __hip_bfloat16 tmp[16] __attribute__((aligned(16)));
#pragma unroll
    for (int u = 0; u < 16; ++u) {
      int pj = f ? (int)p64[jb + u] : p32[jb + u];
      tmp[u] = __float2bfloat16(sx[pj]);
    }
    *(uint4*)(xp + (size_t)m * IN_F + jb)     = *(const uint4*)&tmp[0];
    *(uint4*)(xp + (size_t)m * IN_F + jb + 8) = *(const uint4*)&tmp[8];
  } else {
    int tt = (b - M_ROWS) * 256 + t;
    int o  = tt >> 9;
    int kb = (tt & 511) << 3;
    float s = s_w[(size_t)(kb >> 7) * OUT_F + o];
    const int* wr = w_q + (size_t)o * IN_F + kb;
    int4 w0 = *(const int4*)wr;
    int4 w1 = *(const int4*)(wr + 4);
    __hip_bfloat16 tmp[8] __attribute__((aligned(16)));
    tmp[0] = __float2bfloat16((float)w0.x * s);
    tmp[1] = __float2bfloat16((float)w0.y * s);
    tmp[2] = __float2bfloat16((float)w0.z * s);
    tmp[3] = __float2bfloat16((float)w0.w * s);
    tmp[4] = __float2bfloat16((float)w1.x * s);
    tmp[5] = __float2bfloat16((float)w1.y * s);
    tmp[6] = __float2bfloat16((float)w1.z * s);
    tmp[7] = __float2bfloat16((float)w1.w * s);
    *(uint4*)(wf + (size_t)o * IN_F + kb) = *(const uint4*)tmp;
  }
}

// C[m,o] = sum_k A[m,k]*B[o,k] + bias[o]; A: M x K bf16, B: N x K bf16.
// R5: 128x128 tile, BK=64 DOUBLE-BUFFERED (64 KB LDS), 4 waves (2x2), each wave
// 64x64 via 4x4 MFMA 16x16x32 over 2 k-slices.
// vs R4 (one change): prefetch for step i+1 is issued right after the barrier
// that releases step i's buffer, so each barrier's vmcnt(0) drain waits on a
// load that already had a full compute phase to land. 64 barriers (was 128).
// Staging pattern identical to R4 (quad-contiguous 128B global segments,
// XOR swizzle kc^row&7) -- verified 0 bank conflicts, R1-level coalescing.
__global__ __launch_bounds__(256) void gemm_bt(
    const __hip_bfloat16* __restrict__ A,
    const __hip_bfloat16* __restrict__ B,
    const float* __restrict__ bias,
    float* __restrict__ C) {
  __shared__ __hip_bfloat16 smem[2][16384];  // [parity][A 8192 | B 8192] = 64 KB

  const int tid  = threadIdx.x;
  const int wave = tid >> 6;
  const int lane = tid & 63;
  const int bm = blockIdx.y << 7;
  const int bn = blockIdx.x << 7;
  const int wm = (wave >> 1) << 6;
  const int wn = (wave & 1) << 6;
  const int lrow = lane & 15;
  const int quad = lane >> 4;

  f32x4 acc[4][4] = {};

  // Staging: rounds h=0..3; linear chunk L = h*256 + wave*64 + lane in [0,1024);
  // row = L>>3, kc' = L&7, global kc = kc' ^ (row&7). LDS dest = uniform base
  // (h*256+wave*64)*8 elems + lane*16B (HW scatter).
  const __hip_bfloat16* gA[4];
  const __hip_bfloat16* gB[4];
  int lbase[4];
#pragma unroll
  for (int h = 0; h < 4; ++h) {
    int L   = h * 256 + wave * 64 + lane;
    int row = L >> 3;
    int kc  = (L & 7) ^ (row & 7);
    gA[h] = A + (size_t)(bm + row) * IN_F + kc * 8;
    gB[h] = B + (size_t)(bn + row) * IN_F + kc * 8;
    lbase[h] = (h * 256 + wave * 64) * 8;  // wave-uniform element offset
  }

  auto stage = [&](__hip_bfloat16* buf, int kn) {
#pragma unroll
    for (int h = 0; h < 4; ++h) {
      async16(gA[h] + kn, buf + lbase[h]);
      async16(gB[h] + kn, buf + 8192 + lbase[h]);
    }
  };

  auto compute = [&](const __hip_bfloat16* buf) {
#pragma unroll
    for (int s = 0; s < 2; ++s) {
      const int kcp = ((s << 2) + quad) ^ (lrow & 7);  // swizzled k-chunk pos
      bf16x8 af[4], bfr[4];
#pragma unroll
      for (int i = 0; i < 4; ++i)
        af[i] = *(const bf16x8*)&buf[(wm + i * 16 + lrow) * 64 + kcp * 8];
#pragma unroll
      for (int j = 0; j < 4; ++j)
        bfr[j] = *(const bf16x8*)&buf[8192 + (wn + j * 16 + lrow) * 64 + kcp * 8];
#pragma unroll
      for (int i = 0; i < 4; ++i)
#pragma unroll
        for (int j = 0; j < 4; ++j)
          acc[i][j] = __builtin_amdgcn_mfma_f32_16x16x32_bf16(af[i], bfr[j], acc[i][j], 0, 0, 0);
    }
  };

  stage(smem[0], 0);  // prologue
  for (int k0 = 0; k0 < IN_F; k0 += 128) {
    __syncthreads();               // smem[0]@k0 visible; prev reads of smem[1] done
    stage(smem[1], k0 + 64);       // k0+64 <= 4032 always valid
    compute(smem[0]);
    __syncthreads();               // smem[1]@k0+64 visible; reads of smem[0] done
    if (k0 + 128 < IN_F) stage(smem[0], k0 + 128);
    compute(smem[1]);
  }

  // Epilogue: C/D layout col=lane&15, row=quad*4+reg  [measured m89/m91]
#pragma unroll
  for (int i = 0; i < 4; ++i) {
    int row = bm + wm + i * 16 + quad * 4;
#pragma unroll
    for (int j = 0; j < 4; ++j) {
      int col = bn + wn + j * 16 + lrow;
      float bv = bias[col];
#pragma unroll
      for (int r = 0; r < 4; ++r)
        C[(size_t)(row + r) * OUT_F + col] = acc[i][j][r] + bv;
    }
  }
}

// Correct-but-slow fp32 fallback if workspace is too small for bf16 staging.
__global__ void naive_fallback(const float* __restrict__ x, const int* __restrict__ w_q,
                               const float* __restrict__ s_w, const void* __restrict__ perm_raw,
                               const float* __restrict__ bias, float* __restrict__ out) {
  int t = blockIdx.x * blockDim.x + threadIdx.x;
  int m = t >> 12;
  int o = t & 4095;
  const int f = g_perm_is64;
  const long long* p64 = (const long long*)perm_raw;
  const int*       p32 = (const int*)perm_raw;
  const float* xr = x + (size_t)m * IN_F;
  const int*   wr = w_q + (size_t)o * IN_F;
  float acc = 0.f;
  for (int g = 0; g < NG; ++g) {
    float part = 0.f;
    for (int k = 0; k < GRP; ++k) {
      int j = g * GRP + k;
      int pj = f ? (int)p64[j] : p32[j];
      part += xr[pj] * (float)wr[j];
    }
    acc += part * s_w[(size_t)g * OUT_F + o];
  }
  out[t] = acc + bias[o];
}

extern "C" void kernel_launch(void* const* d_in, const int* in_sizes, int n_in,
                              void* d_out, int out_size, void* d_ws, size_t ws_size,
                              hipStream_t stream) {
  const float* x    = (const float*)d_in[0];
  const int*   w_q  = (const int*)d_in[1];
  const float* s_w  = (const float*)d_in[2];
  const void*  perm = d_in[3];   // int64 or int32 -- detected on device
  const float* bias = (const float*)d_in[4];
  float* out = (float*)d_out;

  const size_t xp_bytes = (size_t)M_ROWS * IN_F * sizeof(__hip_bfloat16);  // 16 MiB
  const size_t wf_bytes = (size_t)OUT_F * IN_F * sizeof(__hip_bfloat16);   // 32 MiB

  if (ws_size < xp_bytes + wf_bytes) {
    decode_flag<<<1, 64, 0, stream>>>(perm);
    naive_fallback<<<(M_ROWS * OUT_F) / 256, 256, 0, stream>>>(x, w_q, s_w, perm, bias, out);
    return;
  }

  __hip_bfloat16* xp = (__hip_bfloat16*)d_ws;
  __hip_bfloat16* wf = (__hip_bfloat16*)((char*)d_ws + xp_bytes);

  prep<<<M_ROWS + (OUT_F * IN_F / 8) / 256, 256, 0, stream>>>(x, w_q, s_w, perm, xp, wf);

  dim3 grid(OUT_F / 128, M_ROWS / 128);  // 32 x 16 = 512 blocks
  gemm_bt<<<grid, 256, 0, stream>>>(xp, wf, bias, out);
}